// Round 2
// baseline (205.797 us; speedup 1.0000x reference)
//
#include <hip/hip_runtime.h>

// VertexDistExtract3D: out[b,k,p] = (R(q_b) * verts[b,k] + pos_b) . dirs[p]
// Folded: out[b,k,p] = verts[b,k] . (R^T dirs[p]) + pos_b . dirs[p]
// B=131072, K=64, P=4, D=199. Memory-bound (~238 MB traffic).

constexpr int B = 131072;
constexpr int K = 64;
constexpr int P = 4;
constexpr int D = 7 + 3 * K; // 199

__global__ __launch_bounds__(256) void vde_kernel(const float* __restrict__ x,
                                                  const float* __restrict__ dirs,
                                                  float* __restrict__ out) {
    const int tid = blockIdx.x * blockDim.x + threadIdx.x;
    const int b = tid >> 6;   // wave-uniform: lane = k
    const int k = tid & 63;

    const float* row = x + (size_t)b * D;

    // Header (wave-uniform broadcast loads)
    const float px = row[0], py = row[1], pz = row[2];
    const float qw = row[3], qx = row[4], qy = row[5], qz = row[6];

    // Rotation matrix (exact reference formula, no normalization)
    const float xx = qx * qx, yy = qy * qy, zz = qz * qz;
    const float xy = qx * qy, xz = qx * qz, yz = qy * qz;
    const float wx = qw * qx, wy = qw * qy, wz = qw * qz;

    const float r00 = 1.0f - 2.0f * (yy + zz);
    const float r01 = 2.0f * (xy - wz);
    const float r02 = 2.0f * (xz + wy);
    const float r10 = 2.0f * (xy + wz);
    const float r11 = 1.0f - 2.0f * (xx + zz);
    const float r12 = 2.0f * (yz - wx);
    const float r20 = 2.0f * (xz - wy);
    const float r21 = 2.0f * (yz + wx);
    const float r22 = 1.0f - 2.0f * (xx + yy);

    // This lane's vertex (contiguous 768B region per wave)
    const float v0 = row[7 + 3 * k];
    const float v1 = row[8 + 3 * k];
    const float v2 = row[9 + 3 * k];

    float4 o;
    float* op = &o.x;
#pragma unroll
    for (int p = 0; p < P; ++p) {
        const float d0 = dirs[p * 3 + 0];
        const float d1 = dirs[p * 3 + 1];
        const float d2 = dirs[p * 3 + 2];
        // m = R^T d_p  (m[j] = sum_i d[i] * R[i][j])
        const float m0 = d0 * r00 + d1 * r10 + d2 * r20;
        const float m1 = d0 * r01 + d1 * r11 + d2 * r21;
        const float m2 = d0 * r02 + d1 * r12 + d2 * r22;
        const float c  = d0 * px + d1 * py + d2 * pz;
        op[p] = v0 * m0 + v1 * m1 + v2 * m2 + c;
    }

    // Coalesced float4 store: lane k writes 16B at (b*64+k)*16
    *reinterpret_cast<float4*>(out + (size_t)tid * 4) = o;
}

extern "C" void kernel_launch(void* const* d_in, const int* in_sizes, int n_in,
                              void* d_out, int out_size, void* d_ws, size_t ws_size,
                              hipStream_t stream) {
    const float* x    = (const float*)d_in[0];
    const float* dirs = (const float*)d_in[1];
    float* out        = (float*)d_out;

    const int total_threads = B * K;          // 8,388,608
    const int block = 256;
    const int grid = total_threads / block;   // 32768
    vde_kernel<<<grid, block, 0, stream>>>(x, dirs, out);
}